// Round 3
// baseline (958.567 us; speedup 1.0000x reference)
//
#include <hip/hip_runtime.h>
#include <stdint.h>

// MaxUnpooling2D scatter-add, two-pass binning with coalesced pair writes.
//
// Evidence R0: scattered 8B pair writes -> 3.6x write amp (962MB vs 268MB).
//   Fixed by LDS bucket-sort + padded contiguous run copy (1239->922us, R1).
// Evidence R1: ~345us of the 922 is the harness's 2.147GB workspace re-poison
//   (fillBufferAligned @6.3TB/s) -- fixed overhead. Our kernels ~575us vs
//   ~210us BW floor. R2 changes: wave shfl scan (3 barriers vs 18),
//   1-lookup phase5 (delta[b]), direct-to-global pad writes, region 32K->16K
//   floats (accumulate 64KiB LDS -> 2 blocks/CU), ulonglong2 pair reads.
// R2 BUG (crash): local scan used PADDED counts -> stage[] overflow by up to
//   3*NB pairs -> LDS corruption -> wild global writes. R3 fix: local scan
//   uses RAW counts (sum == SUB exactly); only the GLOBAL segments are padded
//   (counters advance by hp, runs stay 32B-aligned, counts stay mult-of-4).
//
// B=8, per-batch in = 2^22 elems, per-batch out = 2^24 floats.
// Region = 2^14 floats (64 KiB). 1024 buckets/batch, 8192 total.

#define LOG2_REGION 14
#define REGION      (1 << LOG2_REGION)            // 16384 floats
#define NB          (1 << (24 - LOG2_REGION))     // 1024 buckets per batch
#define NBUCKETS    (8 * NB)                      // 8192
#define SUB         16384                         // elements per pass-1 block
#define BLOCK1      1024                          // == NB: 1 bucket/thread
#define GRID1       ((1 << 25) / SUB)             // 2048 blocks
#define PADM        3                             // pad global runs to 4 pairs
#define BLOCK2      512

// ---------------- Pass 1: LDS bucket-sort sub-chunk, coalesced run writes --
__global__ __launch_bounds__(BLOCK1) void bin_pairs(
    const int*   __restrict__ idx,
    const float* __restrict__ val,
    int*         __restrict__ counters,   // [NBUCKETS], pre-zeroed (padded counts)
    uint64_t*    __restrict__ pairs,      // [NBUCKETS * cap]
    int cap)
{
    __shared__ uint64_t stage[SUB];        // 128 KiB (raw pairs only: sum h == SUB)
    __shared__ int hist[NB];               // raw counts
    __shared__ int pos[NB];                // lstart -> scatter cursor
    __shared__ int delta[NB];              // gbase - lstart (phase5: 1 lookup)
    __shared__ int wsumI[16];

    const int tid  = threadIdx.x;
    const int lane = tid & 63;
    const int wave = tid >> 6;
    const long long start = (long long)blockIdx.x * SUB;   // within one batch
    const int batch = (int)(start >> 22);
    const int4*   idx4 = (const int4*)(idx + start);
    const float4* val4 = (const float4*)(val + start);

    hist[tid] = 0;                         // NB == BLOCK1
    __syncthreads();

    // phase 1: load indices (kept in regs), histogram
    int4 iv[4];
    #pragma unroll
    for (int it = 0; it < 4; ++it) {
        iv[it] = idx4[it * BLOCK1 + tid];
        atomicAdd(&hist[iv[it].x >> LOG2_REGION], 1);
        atomicAdd(&hist[iv[it].y >> LOG2_REGION], 1);
        atomicAdd(&hist[iv[it].z >> LOG2_REGION], 1);
        atomicAdd(&hist[iv[it].w >> LOG2_REGION], 1);
    }
    __syncthreads();

    // phase 2: exclusive scan of RAW counts — wave shfl scan, few barriers
    const int h  = hist[tid];
    const int hp = (h + PADM) & ~PADM;     // global (padded) length
    int v = h;
    #pragma unroll
    for (int d = 1; d < 64; d <<= 1) {
        int u = __shfl_up(v, d);
        if (lane >= d) v += u;
    }
    if (lane == 63) wsumI[wave] = v;
    __syncthreads();
    if (tid < 16) {
        int t = wsumI[tid];
        #pragma unroll
        for (int d = 1; d < 16; d <<= 1) {
            int u = __shfl_up(t, d);
            if (tid >= d) t += u;
        }
        wsumI[tid] = t;                    // inclusive wave totals
    }
    __syncthreads();
    const int lstart = v + (wave ? wsumI[wave - 1] : 0) - h;   // raw exclusive
    pos[tid] = lstart;
    int gbase = 0;
    if (hp) gbase = atomicAdd(&counters[batch * NB + tid], hp);
    delta[tid] = gbase - lstart;

    uint64_t* pb = pairs + (uint64_t)batch * NB * (uint64_t)cap;

    // pads: slots [gbase+h, gbase+hp) of bucket `tid` — written directly to
    // global (lines L2-resident alongside this block's run writes).
    // Harmless zero-adds: offset 0 of region, value +0.0f.
    {
        const uint64_t padp = (uint64_t)(uint32_t)(tid << LOG2_REGION);
        for (int j = h; j < hp; ++j) {
            int dst = gbase + j;
            if (dst < cap) pb[(uint64_t)tid * cap + dst] = padp;
        }
    }
    __syncthreads();

    // phase 3: scatter pairs into LDS stage (bucket-sorted, raw layout)
    #pragma unroll
    for (int it = 0; it < 4; ++it) {
        float4 vv = val4[it * BLOCK1 + tid];
        int   ia[4] = {iv[it].x, iv[it].y, iv[it].z, iv[it].w};
        float fa[4] = {vv.x, vv.y, vv.z, vv.w};
        #pragma unroll
        for (int k = 0; k < 4; ++k) {
            int b = ia[k] >> LOG2_REGION;
            int l = atomicAdd(&pos[b], 1);
            stage[l] = (uint64_t)(uint32_t)ia[k]
                     | ((uint64_t)__float_as_uint(fa[k]) << 32);
        }
    }
    __syncthreads();

    // phase 5: contiguous run copy; dst = i + (gbase - lstart), one LDS lookup
    for (int i = tid; i < SUB; i += BLOCK1) {
        uint64_t p = stage[i];
        int b = (int)((uint32_t)p >> LOG2_REGION);
        int dst = i + delta[b];
        if (dst < cap)
            pb[(uint64_t)b * cap + dst] = p;
    }
}

// ---------------- Pass 2: per-bucket LDS accumulate + coalesced write ------
__global__ __launch_bounds__(BLOCK2) void accumulate(
    const uint64_t* __restrict__ pairs,
    const int*      __restrict__ counters,
    float*          __restrict__ out,
    int cap)
{
    __shared__ float acc[REGION];          // 64 KiB -> 2 blocks/CU
    const int b = blockIdx.x;              // bucket id == output region id
    const int tid = threadIdx.x;

    float4* acc4 = (float4*)acc;
    #pragma unroll
    for (int i = tid; i < REGION / 4; i += BLOCK2)
        acc4[i] = make_float4(0.f, 0.f, 0.f, 0.f);
    __syncthreads();

    int n = counters[b];                   // multiple of 4 by construction
    if (n > cap) n = cap;
    const ulonglong2* p2 = (const ulonglong2*)(pairs + (uint64_t)b * cap);
    for (int i = tid; i < (n >> 1); i += BLOCK2) {
        ulonglong2 v = p2[i];
        atomicAdd(&acc[(int)(v.x & (REGION - 1))],
                  __uint_as_float((uint32_t)(v.x >> 32)));   // ds_add_f32
        atomicAdd(&acc[(int)(v.y & (REGION - 1))],
                  __uint_as_float((uint32_t)(v.y >> 32)));
    }
    __syncthreads();

    // out offset: batch*2^24 + region*2^14 == b * 2^14  (b = batch*1024+region)
    float4* o4 = (float4*)(out + ((long long)b << LOG2_REGION));
    #pragma unroll
    for (int i = tid; i < REGION / 4; i += BLOCK2)
        o4[i] = acc4[i];
}

extern "C" void kernel_launch(void* const* d_in, const int* in_sizes, int n_in,
                              void* d_out, int out_size, void* d_ws, size_t ws_size,
                              hipStream_t stream) {
    const float* in  = (const float*)d_in[0];
    const int*   idx = (const int*)d_in[1];
    float*       out = (float*)d_out;

    int*      counters = (int*)d_ws;
    uint64_t* pairs    = (uint64_t*)((char*)d_ws + 65536);

    // capacity per bucket (pairs), multiple of 4.
    // Expected padded pairs/bucket = 4096 real + <=768 pads ~ 4.9K; 8192 safe.
    int cap = (int)(((ws_size - 65536) / 8) / NBUCKETS);
    if (cap > 8192) cap = 8192;
    cap &= ~PADM;

    hipMemsetAsync(counters, 0, NBUCKETS * sizeof(int), stream);
    bin_pairs<<<GRID1, BLOCK1, 0, stream>>>(idx, in, counters, pairs, cap);
    accumulate<<<NBUCKETS, BLOCK2, 0, stream>>>(pairs, counters, out, cap);
}

// Round 4
// 958.140 us; speedup vs baseline: 1.0004x; 1.0004x over previous
//
#include <hip/hip_runtime.h>
#include <stdint.h>

// MaxUnpooling2D scatter-add, two-pass binning with coalesced pair writes.
//
// Evidence R0: scattered 8B pair writes -> 3.6x write amp (962MB vs 268MB
//   useful); VALUBusy 2%, 2.4TB/s => memory-pipe backpressure. Fixed by LDS
//   bucket-sort + contiguous run copy (1239 -> 922us, R1).
// Evidence R1: ~345us/iter is the harness's 2.147GB workspace re-poison
//   (fillBufferAligned @6.3TB/s) -- fixed overhead we cannot remove.
// Evidence R3: direct-to-global scattered pad writes + phase-serialized
//   1-block/CU bin_pairs made R3 a net regression vs R1 (613 vs 577us for
//   the two kernels; BW floor ~211us).
// R4: (a) DROP PADDING entirely -- unpadded runs tile each bucket segment
//   perfectly contiguously (zero gaps, zero pad traffic, exact counts);
//   pass 2 reads with scalar 8B loads (same bytes, still coalesced).
//   (b) SUB 16384->8192: bin stage 64KiB + 12KiB aux -> 2 blocks/CU so
//   global phases of one block overlap LDS phases of the other.
//
// B=8, per-batch in = 2^22 elems, per-batch out = 2^24 floats.
// Region = 2^14 floats (64 KiB). 1024 buckets/batch, 8192 total.

#define LOG2_REGION 14
#define REGION      (1 << LOG2_REGION)            // 16384 floats
#define NB          (1 << (24 - LOG2_REGION))     // 1024 buckets per batch
#define NBUCKETS    (8 * NB)                      // 8192
#define SUB         8192                          // elements per pass-1 block
#define BLOCK1      1024                          // == NB: 1 bucket/thread
#define GRID1       ((1 << 25) / SUB)             // 4096 blocks
#define BLOCK2      512

// ---------------- Pass 1: LDS bucket-sort sub-chunk, coalesced run writes --
__global__ __launch_bounds__(BLOCK1) void bin_pairs(
    const int*   __restrict__ idx,
    const float* __restrict__ val,
    int*         __restrict__ counters,   // [NBUCKETS], pre-zeroed, EXACT counts
    uint64_t*    __restrict__ pairs,      // [NBUCKETS * cap]
    int cap)
{
    __shared__ uint64_t stage[SUB];        // 64 KiB (sum of raw counts == SUB)
    __shared__ int hist[NB];               // raw counts
    __shared__ int pos[NB];                // lstart -> scatter cursor
    __shared__ int delta[NB];              // gbase - lstart (phase5: 1 lookup)
    __shared__ int wsumI[16];
    // total LDS = 64KiB + 12.06KiB = ~76KiB -> 2 blocks/CU

    const int tid  = threadIdx.x;
    const int lane = tid & 63;
    const int wave = tid >> 6;
    const long long start = (long long)blockIdx.x * SUB;   // within one batch
    const int batch = (int)(start >> 22);
    const int4*   idx4 = (const int4*)(idx + start);
    const float4* val4 = (const float4*)(val + start);

    hist[tid] = 0;                         // NB == BLOCK1
    __syncthreads();

    // phase 1: load indices (kept in regs), histogram
    const int ITER = SUB / 4 / BLOCK1;     // 2
    int4 iv[ITER];
    #pragma unroll
    for (int it = 0; it < ITER; ++it) {
        iv[it] = idx4[it * BLOCK1 + tid];
        atomicAdd(&hist[iv[it].x >> LOG2_REGION], 1);
        atomicAdd(&hist[iv[it].y >> LOG2_REGION], 1);
        atomicAdd(&hist[iv[it].z >> LOG2_REGION], 1);
        atomicAdd(&hist[iv[it].w >> LOG2_REGION], 1);
    }
    __syncthreads();

    // phase 2: exclusive scan of raw counts — wave shfl scan, 3 barriers
    const int h = hist[tid];
    int v = h;
    #pragma unroll
    for (int d = 1; d < 64; d <<= 1) {
        int u = __shfl_up(v, d);
        if (lane >= d) v += u;
    }
    if (lane == 63) wsumI[wave] = v;
    __syncthreads();
    if (tid < 16) {
        int t = wsumI[tid];
        #pragma unroll
        for (int d = 1; d < 16; d <<= 1) {
            int u = __shfl_up(t, d);
            if (tid >= d) t += u;
        }
        wsumI[tid] = t;                    // inclusive wave totals
    }
    __syncthreads();
    const int lstart = v + (wave ? wsumI[wave - 1] : 0) - h;   // exclusive
    pos[tid] = lstart;
    int gbase = 0;
    if (h) gbase = atomicAdd(&counters[batch * NB + tid], h);
    delta[tid] = gbase - lstart;
    __syncthreads();

    // phase 3: scatter pairs into LDS stage (bucket-sorted)
    #pragma unroll
    for (int it = 0; it < ITER; ++it) {
        float4 vv = val4[it * BLOCK1 + tid];
        int   ia[4] = {iv[it].x, iv[it].y, iv[it].z, iv[it].w};
        float fa[4] = {vv.x, vv.y, vv.z, vv.w};
        #pragma unroll
        for (int k = 0; k < 4; ++k) {
            int b = ia[k] >> LOG2_REGION;
            int l = atomicAdd(&pos[b], 1);
            stage[l] = (uint64_t)(uint32_t)ia[k]
                     | ((uint64_t)__float_as_uint(fa[k]) << 32);
        }
    }
    __syncthreads();

    // phase 5: contiguous run copy; dst = i + (gbase - lstart), one LDS lookup.
    // Unpadded: every bucket's segment is tiled gap-free across blocks.
    uint64_t* pb = pairs + (uint64_t)batch * NB * (uint64_t)cap;
    for (int i = tid; i < SUB; i += BLOCK1) {
        uint64_t p = stage[i];
        int b = (int)((uint32_t)p >> LOG2_REGION);
        int dst = i + delta[b];
        if (dst < cap)
            pb[(uint64_t)b * cap + dst] = p;
    }
}

// ---------------- Pass 2: per-bucket LDS accumulate + coalesced write ------
__global__ __launch_bounds__(BLOCK2) void accumulate(
    const uint64_t* __restrict__ pairs,
    const int*      __restrict__ counters,
    float*          __restrict__ out,
    int cap)
{
    __shared__ float acc[REGION];          // 64 KiB -> 2 blocks/CU
    const int b = blockIdx.x;              // bucket id == output region id
    const int tid = threadIdx.x;

    float4* acc4 = (float4*)acc;
    #pragma unroll
    for (int i = tid; i < REGION / 4; i += BLOCK2)
        acc4[i] = make_float4(0.f, 0.f, 0.f, 0.f);
    __syncthreads();

    int n = counters[b];                   // exact pair count
    if (n > cap) n = cap;
    const uint64_t* p = pairs + (uint64_t)b * cap;
    for (int i = tid; i < n; i += BLOCK2) {
        uint64_t v = p[i];
        atomicAdd(&acc[(int)(v & (REGION - 1))],
                  __uint_as_float((uint32_t)(v >> 32)));   // ds_add_f32
    }
    __syncthreads();

    // out offset: batch*2^24 + region*2^14 == b * 2^14  (b = batch*1024+region)
    float4* o4 = (float4*)(out + ((long long)b << LOG2_REGION));
    #pragma unroll
    for (int i = tid; i < REGION / 4; i += BLOCK2)
        o4[i] = acc4[i];
}

extern "C" void kernel_launch(void* const* d_in, const int* in_sizes, int n_in,
                              void* d_out, int out_size, void* d_ws, size_t ws_size,
                              hipStream_t stream) {
    const float* in  = (const float*)d_in[0];
    const int*   idx = (const int*)d_in[1];
    float*       out = (float*)d_out;

    int*      counters = (int*)d_ws;
    uint64_t* pairs    = (uint64_t*)((char*)d_ws + 65536);

    // capacity per bucket (pairs). Expected 4096 avg (sigma ~64); 8192 safe.
    int cap = (int)(((ws_size - 65536) / 8) / NBUCKETS);
    if (cap > 8192) cap = 8192;

    hipMemsetAsync(counters, 0, NBUCKETS * sizeof(int), stream);
    bin_pairs<<<GRID1, BLOCK1, 0, stream>>>(idx, in, counters, pairs, cap);
    accumulate<<<NBUCKETS, BLOCK2, 0, stream>>>(pairs, counters, out, cap);
}

// Round 5
// 907.116 us; speedup vs baseline: 1.0567x; 1.0562x over previous
//
#include <hip/hip_runtime.h>
#include <stdint.h>

// MaxUnpooling2D scatter-add, two-pass binning with coalesced pair writes.
//
// Evidence R0: scattered 8B pair writes -> 3.6x write amp (962MB vs 268MB
//   useful). Fixed by LDS bucket-sort + padded contiguous run copy (R1: 922us
//   total, kernels ~577us after the fixed ~345us workspace re-poison).
// Evidence R3/R4: changing R1's memory layout LOST both times (958us):
//   R3 scattered 8B pad writes to global; R4 dropped padding -> every run
//   boundary misaligned vs the 32B HBM granule (~4M runs x ~32B waste on
//   write AND read). Conclusion: R1's in-stage 32B-aligned padded runs are
//   the right layout. This round keeps R1's memory structure BYTE-IDENTICAL
//   and only removes compute-side overhead:
//     - wave shfl scan (3 barriers) instead of 18-barrier Hillis-Steele
//       (scan runs at 1 block/CU -> barriers are pure dead time)
//     - phase5: one LDS lookup (delta[b]=gbase-lstart) instead of three
//     - pads placed from registers (lstart+h known post-scatter)
//     - accumulate reads pairs as ulonglong2 (counts are mult-of-4)
//
// B=8, per-batch in = 2^22 elems, per-batch out = 2^24 floats.
// Region = 2^15 floats (128 KiB pass-2 tile). 512 buckets/batch, 4096 total.

#define LOG2_REGION 15
#define REGION      (1 << LOG2_REGION)            // 32768 floats
#define NB          (1 << (24 - LOG2_REGION))     // 512 buckets per batch
#define NBUCKETS    (8 * NB)                      // 4096
#define SUB         16384                         // elements per pass-1 block
#define BLOCK1      1024
#define GRID1       ((1 << 25) / SUB)             // 2048 blocks
#define PADM        3                             // pad runs to 4 pairs (32 B)
#define STAGE_CAP   (SUB + PADM * NB)             // 17920 pairs = 140 KiB
#define BLOCK2      1024

// ---------------- Pass 1: LDS bucket-sort sub-chunk, coalesced run writes --
__global__ __launch_bounds__(BLOCK1) void bin_pairs(
    const int*   __restrict__ idx,
    const float* __restrict__ val,
    int*         __restrict__ counters,   // [NBUCKETS], pre-zeroed (padded counts)
    uint64_t*    __restrict__ pairs,      // [NBUCKETS * cap]
    int cap)
{
    __shared__ uint64_t stage[STAGE_CAP];  // 140 KiB (padded local layout)
    __shared__ int hist[NB];               // raw counts
    __shared__ int pos[NB];                // lstart -> scatter cursor
    __shared__ int delta[NB];              // gbase - lstart (phase5: 1 lookup)
    __shared__ int wsumI[16];
    // total LDS ~146 KiB -> 1 block/CU

    const int tid  = threadIdx.x;
    const int lane = tid & 63;
    const int wave = tid >> 6;
    const long long start = (long long)blockIdx.x * SUB;   // within one batch
    const int batch = (int)(start >> 22);
    const int4*   idx4 = (const int4*)(idx + start);
    const float4* val4 = (const float4*)(val + start);

    if (tid < NB) hist[tid] = 0;
    __syncthreads();

    // phase 1: load indices (kept in regs), histogram
    const int ITER = SUB / 4 / BLOCK1;     // 4
    int4 iv[ITER];
    #pragma unroll
    for (int it = 0; it < ITER; ++it) {
        iv[it] = idx4[it * BLOCK1 + tid];
        atomicAdd(&hist[iv[it].x >> LOG2_REGION], 1);
        atomicAdd(&hist[iv[it].y >> LOG2_REGION], 1);
        atomicAdd(&hist[iv[it].z >> LOG2_REGION], 1);
        atomicAdd(&hist[iv[it].w >> LOG2_REGION], 1);
    }
    __syncthreads();

    // phase 2: exclusive scan of PADDED counts (local layout is padded;
    // sum(hp) <= STAGE_CAP by construction). Wave shfl scan, 2 barriers.
    int h = 0, hp = 0;
    if (tid < NB) { h = hist[tid]; hp = (h + PADM) & ~PADM; }
    int v = hp;
    #pragma unroll
    for (int d = 1; d < 64; d <<= 1) {
        int u = __shfl_up(v, d);
        if (lane >= d) v += u;
    }
    if (lane == 63) wsumI[wave] = v;       // waves 8..15 write harmless zeros
    __syncthreads();
    if (tid < 8) {                         // NB/64 == 8 meaningful wave sums
        int t = wsumI[tid];
        #pragma unroll
        for (int d = 1; d < 8; d <<= 1) {
            int u = __shfl_up(t, d);
            if (tid >= d) t += u;
        }
        wsumI[tid] = t;                    // inclusive wave totals; [7]=grand total
    }
    __syncthreads();
    const int lstart = v + (wave ? wsumI[wave - 1] : 0) - hp;  // padded exclusive
    int gbase = 0;
    if (tid < NB) {
        pos[tid] = lstart;                 // scatter cursor
        if (hp) gbase = atomicAdd(&counters[batch * NB + tid], hp);
        delta[tid] = gbase - lstart;
    }
    __syncthreads();

    // phase 3: scatter pairs into LDS stage (bucket-sorted, padded layout)
    #pragma unroll
    for (int it = 0; it < ITER; ++it) {
        float4 vv = val4[it * BLOCK1 + tid];
        int   ia[4] = {iv[it].x, iv[it].y, iv[it].z, iv[it].w};
        float fa[4] = {vv.x, vv.y, vv.z, vv.w};
        #pragma unroll
        for (int k = 0; k < 4; ++k) {
            int b = ia[k] >> LOG2_REGION;
            int l = atomicAdd(&pos[b], 1);
            stage[l] = (uint64_t)(uint32_t)ia[k]
                     | ((uint64_t)__float_as_uint(fa[k]) << 32);
        }
    }
    __syncthreads();

    // phase 4: pads into stage from registers (cursor == lstart+h now).
    // Harmless zero-adds: offset 0 of region `tid`, value +0.0f.
    if (tid < NB) {
        const uint64_t padp = (uint64_t)(uint32_t)(tid << LOG2_REGION);
        #pragma unroll
        for (int j = 0; j < PADM; ++j)
            if (h + j < hp) stage[lstart + h + j] = padp;
    }
    __syncthreads();

    // phase 5: contiguous padded-run copy; dst = i + delta[b], one LDS lookup.
    // Runs are 32B-aligned and 32B-multiples -> every HBM granule full.
    const int total = wsumI[7];
    uint64_t* pb = pairs + (uint64_t)batch * NB * (uint64_t)cap;
    for (int i = tid; i < total; i += BLOCK1) {
        uint64_t p = stage[i];
        int b = (int)((uint32_t)p >> LOG2_REGION);
        int dst = i + delta[b];
        if (dst < cap)
            pb[(uint64_t)b * cap + dst] = p;
    }
}

// ---------------- Pass 2: per-bucket LDS accumulate + coalesced write ------
__global__ __launch_bounds__(BLOCK2) void accumulate(
    const uint64_t* __restrict__ pairs,
    const int*      __restrict__ counters,
    float*          __restrict__ out,
    int cap)
{
    __shared__ float acc[REGION];          // 128 KiB
    const int b = blockIdx.x;              // bucket id == output region id
    const int tid = threadIdx.x;

    float4* acc4 = (float4*)acc;
    #pragma unroll
    for (int i = tid; i < REGION / 4; i += BLOCK2)
        acc4[i] = make_float4(0.f, 0.f, 0.f, 0.f);
    __syncthreads();

    int n = counters[b];                   // multiple of 4 by construction
    if (n > cap) n = cap;
    const ulonglong2* p2 = (const ulonglong2*)(pairs + (uint64_t)b * cap);
    for (int i = tid; i < (n >> 1); i += BLOCK2) {
        ulonglong2 v = p2[i];
        atomicAdd(&acc[(int)(v.x & (REGION - 1))],
                  __uint_as_float((uint32_t)(v.x >> 32)));   // ds_add_f32
        atomicAdd(&acc[(int)(v.y & (REGION - 1))],
                  __uint_as_float((uint32_t)(v.y >> 32)));
    }
    __syncthreads();

    // out offset: batch*2^24 + region*2^15 == b * 2^15  (b = batch*512+region)
    float4* o4 = (float4*)(out + ((long long)b << LOG2_REGION));
    #pragma unroll
    for (int i = tid; i < REGION / 4; i += BLOCK2)
        o4[i] = acc4[i];
}

extern "C" void kernel_launch(void* const* d_in, const int* in_sizes, int n_in,
                              void* d_out, int out_size, void* d_ws, size_t ws_size,
                              hipStream_t stream) {
    const float* in  = (const float*)d_in[0];
    const int*   idx = (const int*)d_in[1];
    float*       out = (float*)d_out;

    int*      counters = (int*)d_ws;
    uint64_t* pairs    = (uint64_t*)((char*)d_ws + 65536);

    // capacity per bucket (pairs), multiple of 4.
    // Expected padded pairs/bucket = 8192 real + <=768 pads; 16384 is safe.
    int cap = (int)(((ws_size - 65536) / 8) / NBUCKETS);
    if (cap > 16384) cap = 16384;
    cap &= ~PADM;

    hipMemsetAsync(counters, 0, NBUCKETS * sizeof(int), stream);
    bin_pairs<<<GRID1, BLOCK1, 0, stream>>>(idx, in, counters, pairs, cap);
    accumulate<<<NBUCKETS, BLOCK2, 0, stream>>>(pairs, counters, out, cap);
}